// Round 19
// baseline (77.197 us; speedup 1.0000x reference)
//
#include <hip/hip_runtime.h>
#include <hip/hip_bf16.h>
#include <stdint.h>

#define DIMC 128
#define S_LEN 4096
#define NHEAD 8
#define HDIM 16

typedef __attribute__((ext_vector_type(8))) short bf8;          // 8 bf16 (MFMA A/B frag)
typedef __attribute__((ext_vector_type(8))) unsigned short us8;
typedef __attribute__((ext_vector_type(4))) float f4;
typedef __attribute__((ext_vector_type(16))) float f16v;
typedef __attribute__((ext_vector_type(4))) unsigned short u16x4;
typedef __attribute__((ext_vector_type(4))) unsigned int u32x4;

static __device__ __forceinline__ unsigned short f2bf(float f) {
    return __builtin_bit_cast(unsigned short, __float2bfloat16(f));
}
static __device__ __forceinline__ f16v zero_f16v() {
    f16v z;
#pragma unroll
    for (int i = 0; i < 16; ++i) z[i] = 0.f;
    return z;
}
static __device__ __forceinline__ unsigned cvtpk(float lo, float hi) {
    unsigned r;
    asm("v_cvt_pk_bf16_f32 %0, %1, %2" : "=v"(r) : "v"(lo), "v"(hi));
    return r;
}
static __device__ __forceinline__ void plswap(unsigned &a, unsigned &b) {
    // R2-verified in the P-pack path (operands hold distinct data -> no aliasing)
    asm("v_permlane32_swap_b32 %0, %1" : "+v"(a), "+v"(b));
}

// ---------------- Kernel 1: LayerNorm(+pos) + one projection per block ----------------
// grid 384: which = bx>>7: 0 -> feat_a->q, 1 -> feat_b->k, 2 -> feat_b->v
__global__ __launch_bounds__(256) void k_lnqkv(
    const float* __restrict__ feat_a, const float* __restrict__ feat_b,
    const float* __restrict__ wq, const float* __restrict__ wkv,
    const float* __restrict__ g1, const float* __restrict__ b1,
    const float* __restrict__ g2, const float* __restrict__ b2,
    const float* __restrict__ pos,
    unsigned short* __restrict__ qo, unsigned short* __restrict__ ko,
    unsigned short* __restrict__ vto)
{
    __shared__ __align__(16) float Xs[DIMC * 64];            // 32KB raw tile, aliased by Wl later
    __shared__ __align__(16) unsigned short Aln[64 * DIMC];  // 16KB LN'd bf16, swizzled
    __shared__ float gm[DIMC], bt[DIMC];
    __shared__ float mu_s[64], rs_s[64];
    __shared__ float red[8][64];
    unsigned short* Wl = (unsigned short*)Xs;                // alias (used after Xs is dead)

    const int tid = threadIdx.x;
    const int bx = blockIdx.x;
    const int which = bx >> 7;          // 0:q 1:k 2:v
    const int rr_ = bx & 127;
    const int b = rr_ >> 6;
    const int s0 = (rr_ & 63) << 6;

    if (tid < DIMC) {
        gm[tid] = which ? g2[tid] : g1[tid];
        bt[tid] = (which ? b2[tid] : b1[tid]) + pos[tid];
    }
    const float* src = (which ? feat_b : feat_a) + (size_t)b * DIMC * S_LEN + s0;
#pragma unroll
    for (int i = 0; i < 32; ++i) {                 // [128 c][64 s] coalesced
        int idx = tid + i * 256;
        int c = idx >> 6, sl = idx & 63;
        Xs[c * 64 + sl] = src[c * S_LEN + sl];
    }
    __syncthreads();
    {   // LN stats, 4 partial c-ranges per position
        int part = tid >> 6, sl = tid & 63;
        float sum = 0.f, sq = 0.f;
        for (int c = part * 32; c < part * 32 + 32; ++c) {
            float v = Xs[c * 64 + sl];
            sum += v; sq += v * v;
        }
        red[part][sl] = sum; red[4 + part][sl] = sq;
    }
    __syncthreads();
    if (tid < 64) {
        float s = red[0][tid] + red[1][tid] + red[2][tid] + red[3][tid];
        float q = red[4][tid] + red[5][tid] + red[6][tid] + red[7][tid];
        float mu = s * (1.f / 128.f);
        float var = q * (1.f / 128.f) - mu * mu;
        mu_s[tid] = mu;
        rs_s[tid] = rsqrtf(var + 1e-5f);
    }
    __syncthreads();
    // normalize -> Aln bf16, XOR-swizzled 16B chunks within each 256B row
#pragma unroll
    for (int i = 0; i < 16; ++i) {
        int idx = tid + i * 256;           // 4096 = 64 cpair x 64 s
        int sl = idx & 63, cp = idx >> 6;
        int c = cp * 2;
        float mu = mu_s[sl], rs = rs_s[sl];
        float v0 = (Xs[c * 64 + sl] - mu) * rs * gm[c] + bt[c];
        float v1 = (Xs[(c + 1) * 64 + sl] - mu) * rs * gm[c + 1] + bt[c + 1];
        unsigned int pk = (unsigned int)f2bf(v0) | ((unsigned int)f2bf(v1) << 16);
        int chunk = (c >> 3) ^ (sl & 7);
        ((unsigned int*)Aln)[sl * 64 + chunk * 4 + ((c & 7) >> 1)] = pk;
    }
    __syncthreads();                       // Xs dead from here; Wl alias live

    const int lane = tid & 63;
    const int w = tid >> 6;
    const float* W = (which == 0) ? wq : (wkv + (size_t)(which - 1) * DIMC * DIMC);
#pragma unroll
    for (int i = 0; i < 32; ++i) {     // weights [n][c] fp32 -> bf16 swizzled LDS
        int idx = tid + i * 256;
        int cp = idx & 63, n = idx >> 6, c = cp * 2;
        float2 wv = *(const float2*)(W + n * DIMC + c);
        unsigned int pk = (unsigned int)f2bf(wv.x) | ((unsigned int)f2bf(wv.y) << 16);
        int chunk = (c >> 3) ^ (n & 7);
        ((unsigned int*)Wl)[n * 64 + chunk * 4 + ((c & 7) >> 1)] = pk;
    }
    __syncthreads();
    f4 acc[8];
#pragma unroll
    for (int nt = 0; nt < 8; ++nt) { acc[nt][0]=0.f; acc[nt][1]=0.f; acc[nt][2]=0.f; acc[nt][3]=0.f; }
#pragma unroll
    for (int kk = 0; kk < 4; ++kk) {
        int arow = w * 16 + (lane & 15);
        int ach = (kk * 4 + (lane >> 4)) ^ (arow & 7);
        bf8 af = *(const bf8*)(Aln + arow * DIMC + ach * 8);
#pragma unroll
        for (int nt = 0; nt < 8; ++nt) {
            int brow = nt * 16 + (lane & 15);
            int bch = (kk * 4 + (lane >> 4)) ^ (brow & 7);
            bf8 bfr = *(const bf8*)(Wl + brow * DIMC + bch * 8);
            acc[nt] = __builtin_amdgcn_mfma_f32_16x16x32_bf16(af, bfr, acc[nt], 0, 0, 0);
        }
    }
    // epilogue: C layout col=lane&15 (=n within tile=d), row=(lane>>4)*4+r (=s)
    int d = lane & 15;
    int sloc = s0 + w * 16 + ((lane >> 4) << 2);
#pragma unroll
    for (int nt = 0; nt < 8; ++nt) {
        int headg = b * NHEAD + nt;    // head == nt (16-wide n-tiles)
        if (which == 0) {
            const float QSC = 0.25f * 1.44269504088896f;  // fold scale*log2e into Q
#pragma unroll
            for (int r2 = 0; r2 < 4; ++r2)
                qo[((size_t)headg * S_LEN + sloc + r2) * HDIM + d] = f2bf(acc[nt][r2] * QSC);
        } else if (which == 1) {
#pragma unroll
            for (int r2 = 0; r2 < 4; ++r2)
                ko[((size_t)headg * S_LEN + sloc + r2) * HDIM + d] = f2bf(acc[nt][r2]);
        } else {
            u16x4 pv;
#pragma unroll
            for (int r2 = 0; r2 < 4; ++r2) pv[r2] = f2bf(acc[nt][r2]);
            *(u16x4*)(vto + ((size_t)headg * HDIM + d) * S_LEN + sloc) = pv;   // V^T [bh][d][s]
        }
    }
}

// ---------------- Kernel 2: flash attention, fixed m=0 (no max tracking) ----------------
// R13-verified tail: p=exp2(st) directly (LN-bounded scores), f32 lsum, end-normalize.
static __device__ __forceinline__ void attn_tail(
    f16v& st, const bf8& vfA, const bf8& vfB, float& lsum_h, f16v& o)
{
#pragma unroll
    for (int r = 0; r < 16; ++r) st[r] = __builtin_amdgcn_exp2f(st[r]);
    float q0 = (st[0] + st[1]) + (st[2] + st[3]);
    float q1 = (st[4] + st[5]) + (st[6] + st[7]);
    float q2 = (st[8] + st[9]) + (st[10] + st[11]);
    float q3 = (st[12] + st[13]) + (st[14] + st[15]);
    lsum_h += (q0 + q1) + (q2 + q3);   // per-half partial; cross-half combine deferred
    // pack P^T B-frags (R2-verified): kp chunk 0..15
    unsigned a0 = cvtpk(st[0], st[1]);
    unsigned a1 = cvtpk(st[2], st[3]);
    unsigned a2 = cvtpk(st[4], st[5]);
    unsigned a3 = cvtpk(st[6], st[7]);
    plswap(a0, a2); plswap(a1, a3);
    u32x4 tA; tA[0] = a0; tA[1] = a1; tA[2] = a2; tA[3] = a3;
    o = __builtin_amdgcn_mfma_f32_32x32x16_bf16(vfA, __builtin_bit_cast(bf8, tA), o, 0, 0, 0);
    // kp chunk 16..31
    unsigned b0 = cvtpk(st[8], st[9]);
    unsigned b1 = cvtpk(st[10], st[11]);
    unsigned b2 = cvtpk(st[12], st[13]);
    unsigned b3 = cvtpk(st[14], st[15]);
    plswap(b0, b2); plswap(b1, b3);
    u32x4 tB; tB[0] = b0; tB[1] = b1; tB[2] = b2; tB[3] = b3;
    o = __builtin_amdgcn_mfma_f32_32x32x16_bf16(vfB, __builtin_bit_cast(bf8, tB), o, 0, 0, 0);
}

// grid 512*NS linear (XCD-swizzled); block 2 waves * 64 q-rows
template <int NS>
__global__ __launch_bounds__(128, 4) void k_attn(
    const unsigned short* __restrict__ qo,
    const unsigned short* __restrict__ ko,
    const unsigned short* __restrict__ vto,
    unsigned short* __restrict__ xo,
    float* __restrict__ opart, float* __restrict__ lpart)
{
    const int tid = threadIdx.x;
    const int lane = tid & 63;
    const int w = tid >> 6;                  // 0..1
    // XCD-aware remap: all 64*NS blocks of a bh land on one XCD (2 bh per XCD);
    // per-bh K/V (256KB) stays L2-resident (R8-verified: FETCH 17.8 -> 3.1 MB).
    const int lid = blockIdx.x;              // [0, 512*NS)
    const int xcd = lid & 7;
    const int j = lid >> 3;                  // [0, 64*NS)
    const int bh = xcd * 2 + j / (32 * NS);
    const int r = j % (32 * NS);
    const int qb = r & 31;                   // 32 q-tiles of 128
    const int sp = r >> 5;                   // [0, NS)
    const int s0 = qb * 128 + w * 64;
    const int b = bh >> 3, h = bh & 7;
    const int kt0 = sp * (S_LEN / NS);
    const int kt1 = kt0 + S_LEN / NS;

    const unsigned short* Qp = qo + (size_t)bh * S_LEN * HDIM;
    const unsigned short* Kp = ko + (size_t)bh * S_LEN * HDIM;
    const unsigned short* Vp = vto + (size_t)bh * HDIM * S_LEN;

    const int l31 = lane & 31, l15 = lane & 15, hi = lane >> 5;
    const unsigned short* vrow = Vp + (size_t)l15 * S_LEN + hi * 8;

    // Q B-frags for the two q-blocks: lane holds Q[s0(+32)+l31][d = hi*8 + j]
    bf8 qfA = *(const bf8*)(Qp + (size_t)(s0 + l31) * HDIM + hi * 8);
    bf8 qfB = *(const bf8*)(Qp + (size_t)(s0 + 32 + l31) * HDIM + hi * 8);

    float lsumA = 0.f, lsumB = 0.f;
    f16v oA = zero_f16v();              // rows r=0..7 useful (d = (r&3)+8*(r>>2)+4*hi)
    f16v oB = zero_f16v();
    const f16v zacc = zero_f16v();      // single persistent zero C operand

    // prefetch: K one tile ahead, V for tile 0
    bf8 kf   = *(const bf8*)(Kp + (size_t)(kt0 + l31) * HDIM + hi * 8);
    bf8 kf_n = *(const bf8*)(Kp + (size_t)(kt0 + 32 + l31) * HDIM + hi * 8);
    bf8 vfA_c = *(const bf8*)(vrow + kt0);
    bf8 vfB_c = *(const bf8*)(vrow + kt0 + 16);

    for (int kt = kt0; kt < kt1; kt += 32) {
        f16v stA = __builtin_amdgcn_mfma_f32_32x32x16_bf16(kf, qfA, zacc, 0, 0, 0);
        bf8 kf_n2 = *(const bf8*)(Kp + (size_t)(kt + 64 + l31) * HDIM + hi * 8); // tail overread in ws
        bf8 vfA_n = *(const bf8*)(vrow + kt + 32);
        bf8 vfB_n = *(const bf8*)(vrow + kt + 48);
        attn_tail(stA, vfA_c, vfB_c, lsumA, oA);
        f16v stB = __builtin_amdgcn_mfma_f32_32x32x16_bf16(kf, qfB, zacc, 0, 0, 0);
        attn_tail(stB, vfA_c, vfB_c, lsumB, oB);

        kf = kf_n; kf_n = kf_n2;
        vfA_c = vfA_n; vfB_c = vfB_n;
    }

    float lsA = lsumA + __shfl_xor(lsumA, 32);   // deferred cross-half combine
    float lsB = lsumB + __shfl_xor(lsumB, 32);

    if (NS == 1) {
        float invA = 1.f / lsA, invB = 1.f / lsB;
        u16x4 a_lo, a_hi, b_lo, b_hi;
#pragma unroll
        for (int r2 = 0; r2 < 4; ++r2) {
            a_lo[r2] = f2bf(oA[r2] * invA);
            a_hi[r2] = f2bf(oA[r2 + 4] * invA);
            b_lo[r2] = f2bf(oB[r2] * invB);
            b_hi[r2] = f2bf(oB[r2 + 4] * invB);
        }
        size_t baseA = ((size_t)b * S_LEN + s0 + l31) * DIMC + h * HDIM;
        size_t baseB = ((size_t)b * S_LEN + s0 + 32 + l31) * DIMC + h * HDIM;
        *(u16x4*)(xo + baseA + 4 * hi) = a_lo;
        *(u16x4*)(xo + baseA + 8 + 4 * hi) = a_hi;
        *(u16x4*)(xo + baseB + 4 * hi) = b_lo;
        *(u16x4*)(xo + baseB + 8 + 4 * hi) = b_hi;
    } else {
        size_t rbA = ((size_t)(sp * 16 + bh) * S_LEN + s0 + l31) * 16;
        size_t rbB = rbA + 32 * 16;
        f4 xa0, xa1, xb0, xb1;
#pragma unroll
        for (int r2 = 0; r2 < 4; ++r2) {
            xa0[r2] = oA[r2]; xa1[r2] = oA[r2 + 4];
            xb0[r2] = oB[r2]; xb1[r2] = oB[r2 + 4];
        }
        *(f4*)(opart + rbA + 4 * hi) = xa0;
        *(f4*)(opart + rbA + 8 + 4 * hi) = xa1;
        *(f4*)(opart + rbB + 4 * hi) = xb0;
        *(f4*)(opart + rbB + 8 + 4 * hi) = xb1;
        if (!hi) {
            lpart[(size_t)(sp * 16 + bh) * S_LEN + s0 + l31] = lsA;
            lpart[(size_t)(sp * 16 + bh) * S_LEN + s0 + 32 + l31] = lsB;
        }
    }
}

// ---------------- Kernel 2b: combine NS KV-splits (NS=1 fallback path only) ----------------
template <int NS>
__global__ __launch_bounds__(256) void k_combine(
    const float* __restrict__ op, const float* __restrict__ lp,
    unsigned short* __restrict__ xo)
{
    int idx = blockIdx.x * 256 + threadIdx.x;   // 262144 = 65536 rows x 4 d-chunks
    int row = idx >> 2;                          // bh*4096 + s
    int dc = (idx & 3) * 4;
    int bh = row >> 12, s = row & 4095;
    int b = bh >> 3, h = bh & 7;
    float den = 0.f;
#pragma unroll
    for (int i = 0; i < NS; ++i) den += lp[row + (size_t)i * (16 << 12)];
    float inv = 1.f / den;
    f4 acc;
#pragma unroll
    for (int jj = 0; jj < 4; ++jj) acc[jj] = 0.f;
#pragma unroll
    for (int i = 0; i < NS; ++i) {
        f4 oi = *(const f4*)(op + ((size_t)row + (size_t)i * (16 << 12)) * 16 + dc);
#pragma unroll
        for (int jj = 0; jj < 4; ++jj) acc[jj] += oi[jj];
    }
    u16x4 rr;
#pragma unroll
    for (int jj = 0; jj < 4; ++jj) rr[jj] = f2bf(acc[jj] * inv);
    *(u16x4*)(xo + ((size_t)b * S_LEN + s) * DIMC + h * HDIM + dc) = rr;
}

// ---------------- Kernel 3 (fused): combine NS splits + projection + bias + [b,c,s] store ----
// A-operand built directly from opart/lp: af covers 8 channels of ONE head
// (c = kk*32 + g4*8 + 0..7 -> h = c>>4, d0 = c&15 in {0,8}).
template <int NS>
__global__ __launch_bounds__(256) void k_proj_fused(
    const float* __restrict__ op, const float* __restrict__ lp,
    const float* __restrict__ wp, const float* __restrict__ bp,
    float* __restrict__ out)
{
    __shared__ __align__(16) unsigned short Wl[64 * DIMC];   // 16KB
    const int tid = threadIdx.x, lane = tid & 63, w = tid >> 6;
    const int m0 = (blockIdx.x >> 1) * 64;
    const int nh = blockIdx.x & 1;
#pragma unroll
    for (int i = 0; i < 16; ++i) {
        int idx = tid + i * 256;
        int cp = idx & 63, n = idx >> 6, c = cp * 2;
        float2 wv = *(const float2*)(wp + (size_t)(nh * 64 + n) * DIMC + c);
        unsigned int pk = (unsigned int)f2bf(wv.x) | ((unsigned int)f2bf(wv.y) << 16);
        int chunk = (c >> 3) ^ (n & 7);
        ((unsigned int*)Wl)[n * 64 + chunk * 4 + ((c & 7) >> 1)] = pk;
    }
    __syncthreads();
    f4 acc[4];
#pragma unroll
    for (int nt = 0; nt < 4; ++nt) { acc[nt][0]=0.f; acc[nt][1]=0.f; acc[nt][2]=0.f; acc[nt][3]=0.f; }
    const int arow = m0 + w * 16 + (lane & 15);
    const int g4 = lane >> 4;
    const int bb0 = arow >> 12, ss0 = arow & 4095;   // batch, seq of this A-row
#pragma unroll
    for (int kk = 0; kk < 4; ++kk) {
        // reconstruct af = x[arow][c0..c0+7] from NS split partials (fixed m=0: plain sums)
        int c0 = kk * 32 + g4 * 8;
        int hh = c0 >> 4;                    // head of these 8 channels
        int d0 = c0 & 15;                    // 0 or 8
        int bh_ = bb0 * NHEAD + hh;
        float den = 0.f;
        f4 alo, ahi;
#pragma unroll
        for (int jj = 0; jj < 4; ++jj) { alo[jj] = 0.f; ahi[jj] = 0.f; }
#pragma unroll
        for (int i = 0; i < NS; ++i) {
            size_t row = (size_t)(i * 16 + bh_) * S_LEN + ss0;
            den += lp[row];
            f4 lo = *(const f4*)(op + row * 16 + d0);
            f4 hi = *(const f4*)(op + row * 16 + d0 + 4);
#pragma unroll
            for (int jj = 0; jj < 4; ++jj) { alo[jj] += lo[jj]; ahi[jj] += hi[jj]; }
        }
        float inv = 1.f / den;
        us8 av;
#pragma unroll
        for (int jj = 0; jj < 4; ++jj) {
            av[jj] = f2bf(alo[jj] * inv);
            av[jj + 4] = f2bf(ahi[jj] * inv);
        }
        bf8 af = __builtin_bit_cast(bf8, av);
#pragma unroll
        for (int nt = 0; nt < 4; ++nt) {
            int brow = nt * 16 + (lane & 15);
            int bch = (kk * 4 + g4) ^ (brow & 7);
            bf8 bfr = *(const bf8*)(Wl + brow * DIMC + bch * 8);
            acc[nt] = __builtin_amdgcn_mfma_f32_16x16x32_bf16(af, bfr, acc[nt], 0, 0, 0);
        }
    }
    int sl0 = m0 + w * 16 + ((lane >> 4) << 2);
    int bb = sl0 >> 12, ss = sl0 & 4095;
#pragma unroll
    for (int nt = 0; nt < 4; ++nt) {
        int n = nh * 64 + nt * 16 + (lane & 15);
        float bias = bp[n];
        f4 v;
#pragma unroll
        for (int r2 = 0; r2 < 4; ++r2) v[r2] = acc[nt][r2] + bias;
        *(f4*)(out + ((size_t)bb * DIMC + n) * S_LEN + ss) = v;   // 4 consecutive s, float4
    }
}

// ---------------- Kernel 3 (NS=1 fallback): projection from xas ----------------
__global__ __launch_bounds__(256) void k_proj(
    const unsigned short* __restrict__ xa, const float* __restrict__ wp,
    const float* __restrict__ bp, float* __restrict__ out)
{
    __shared__ __align__(16) unsigned short Wl[64 * DIMC];   // 16KB
    const int tid = threadIdx.x, lane = tid & 63, w = tid >> 6;
    const int m0 = (blockIdx.x >> 1) * 64;
    const int nh = blockIdx.x & 1;
#pragma unroll
    for (int i = 0; i < 16; ++i) {
        int idx = tid + i * 256;
        int cp = idx & 63, n = idx >> 6, c = cp * 2;
        float2 wv = *(const float2*)(wp + (size_t)(nh * 64 + n) * DIMC + c);
        unsigned int pk = (unsigned int)f2bf(wv.x) | ((unsigned int)f2bf(wv.y) << 16);
        int chunk = (c >> 3) ^ (n & 7);
        ((unsigned int*)Wl)[n * 64 + chunk * 4 + ((c & 7) >> 1)] = pk;
    }
    __syncthreads();
    f4 acc[4];
#pragma unroll
    for (int nt = 0; nt < 4; ++nt) { acc[nt][0]=0.f; acc[nt][1]=0.f; acc[nt][2]=0.f; acc[nt][3]=0.f; }
    int arow = m0 + w * 16 + (lane & 15);
#pragma unroll
    for (int kk = 0; kk < 4; ++kk) {
        bf8 af = *(const bf8*)(xa + (size_t)arow * DIMC + kk * 32 + (lane >> 4) * 8);
#pragma unroll
        for (int nt = 0; nt < 4; ++nt) {
            int brow = nt * 16 + (lane & 15);
            int bch = (kk * 4 + (lane >> 4)) ^ (brow & 7);
            bf8 bfr = *(const bf8*)(Wl + brow * DIMC + bch * 8);
            acc[nt] = __builtin_amdgcn_mfma_f32_16x16x32_bf16(af, bfr, acc[nt], 0, 0, 0);
        }
    }
    int sl0 = m0 + w * 16 + ((lane >> 4) << 2);
    int bb = sl0 >> 12, ss = sl0 & 4095;
#pragma unroll
    for (int nt = 0; nt < 4; ++nt) {
        int n = nh * 64 + nt * 16 + (lane & 15);
        float bias = bp[n];
        f4 v;
#pragma unroll
        for (int r2 = 0; r2 < 4; ++r2) v[r2] = acc[nt][r2] + bias;
        *(f4*)(out + ((size_t)bb * DIMC + n) * S_LEN + ss) = v;   // 4 consecutive s, float4
    }
}

extern "C" void kernel_launch(void* const* d_in, const int* in_sizes, int n_in,
                              void* d_out, int out_size, void* d_ws, size_t ws_size,
                              hipStream_t stream) {
    const float* feat_a = (const float*)d_in[0];
    const float* feat_b = (const float*)d_in[1];
    const float* wq     = (const float*)d_in[2];
    const float* wkv    = (const float*)d_in[3];
    const float* wproj  = (const float*)d_in[4];
    const float* bproj  = (const float*)d_in[5];
    const float* g1     = (const float*)d_in[6];
    const float* b1     = (const float*)d_in[7];
    const float* g2     = (const float*)d_in[8];
    const float* b2     = (const float*)d_in[9];
    const float* pos    = (const float*)d_in[10];
    float* out = (float*)d_out;

    unsigned short* ws = (unsigned short*)d_ws;
    unsigned short* qs  = ws;                    // 2MB bf16 [16][4096][16]
    unsigned short* kss = ws + (1u << 20);       // 2MB
    unsigned short* vts = ws + (2u << 20);       // 2MB V^T [16][16][4096]
    unsigned short* xas = ws + (3u << 20);       // 2MB attn out bf16 (NS=1 path)
    float*  opart = (float*)(ws + (4u << 20));   // NS*4MB f32 at byte 8MB
    float*  lp2   = (float*)(ws + (8u << 20));   // bytes 16..16.5MB (NS=2)
    float*  lp4   = (float*)(ws + (12u << 20));  // bytes 24..25MB (NS=4)

    k_lnqkv<<<dim3(384), dim3(256), 0, stream>>>(feat_a, feat_b, wq, wkv, g1, b1, g2, b2, pos,
                                                 qs, kss, vts);
    if (ws_size >= ((size_t)17 << 20)) {         // prefer NS=2: half the partial traffic
        k_attn<2><<<dim3(1024), dim3(128), 0, stream>>>(qs, kss, vts, xas, opart, lp2);
        k_proj_fused<2><<<dim3(256), dim3(256), 0, stream>>>(opart, lp2, wproj, bproj, out);
    } else {
        k_attn<1><<<dim3(512), dim3(128), 0, stream>>>(qs, kss, vts, xas, opart, lp2);
        k_proj<<<dim3(256), dim3(256), 0, stream>>>(xas, wproj, bproj, out);
    }
}

// Round 20
// 68.187 us; speedup vs baseline: 1.1321x; 1.1321x over previous
//
#include <hip/hip_runtime.h>
#include <hip/hip_bf16.h>
#include <stdint.h>

#define DIMC 128
#define S_LEN 4096
#define NHEAD 8
#define HDIM 16

typedef __attribute__((ext_vector_type(8))) short bf8;          // 8 bf16 (MFMA A/B frag)
typedef __attribute__((ext_vector_type(8))) unsigned short us8;
typedef __attribute__((ext_vector_type(4))) float f4;
typedef __attribute__((ext_vector_type(16))) float f16v;
typedef __attribute__((ext_vector_type(4))) unsigned short u16x4;
typedef __attribute__((ext_vector_type(4))) unsigned int u32x4;

static __device__ __forceinline__ unsigned short f2bf(float f) {
    return __builtin_bit_cast(unsigned short, __float2bfloat16(f));
}
static __device__ __forceinline__ f16v zero_f16v() {
    f16v z;
#pragma unroll
    for (int i = 0; i < 16; ++i) z[i] = 0.f;
    return z;
}
static __device__ __forceinline__ unsigned cvtpk(float lo, float hi) {
    unsigned r;
    asm("v_cvt_pk_bf16_f32 %0, %1, %2" : "=v"(r) : "v"(lo), "v"(hi));
    return r;
}
static __device__ __forceinline__ void plswap(unsigned &a, unsigned &b) {
    // R2-verified in the P-pack path (operands hold distinct data -> no aliasing)
    asm("v_permlane32_swap_b32 %0, %1" : "+v"(a), "+v"(b));
}

// ---------------- Kernel 1: LayerNorm(+pos) + one projection per block ----------------
// grid 384: which = bx>>7: 0 -> feat_a->q, 1 -> feat_b->k, 2 -> feat_b->v
__global__ __launch_bounds__(256) void k_lnqkv(
    const float* __restrict__ feat_a, const float* __restrict__ feat_b,
    const float* __restrict__ wq, const float* __restrict__ wkv,
    const float* __restrict__ g1, const float* __restrict__ b1,
    const float* __restrict__ g2, const float* __restrict__ b2,
    const float* __restrict__ pos,
    unsigned short* __restrict__ qo, unsigned short* __restrict__ ko,
    unsigned short* __restrict__ vto)
{
    __shared__ __align__(16) float Xs[DIMC * 64];            // 32KB raw tile, aliased by Wl later
    __shared__ __align__(16) unsigned short Aln[64 * DIMC];  // 16KB LN'd bf16, swizzled
    __shared__ float gm[DIMC], bt[DIMC];
    __shared__ float mu_s[64], rs_s[64];
    __shared__ float red[8][64];
    unsigned short* Wl = (unsigned short*)Xs;                // alias (used after Xs is dead)

    const int tid = threadIdx.x;
    const int bx = blockIdx.x;
    const int which = bx >> 7;          // 0:q 1:k 2:v
    const int rr_ = bx & 127;
    const int b = rr_ >> 6;
    const int s0 = (rr_ & 63) << 6;

    if (tid < DIMC) {
        gm[tid] = which ? g2[tid] : g1[tid];
        bt[tid] = (which ? b2[tid] : b1[tid]) + pos[tid];
    }
    const float* src = (which ? feat_b : feat_a) + (size_t)b * DIMC * S_LEN + s0;
#pragma unroll
    for (int i = 0; i < 32; ++i) {                 // [128 c][64 s] coalesced
        int idx = tid + i * 256;
        int c = idx >> 6, sl = idx & 63;
        Xs[c * 64 + sl] = src[c * S_LEN + sl];
    }
    __syncthreads();
    {   // LN stats, 4 partial c-ranges per position
        int part = tid >> 6, sl = tid & 63;
        float sum = 0.f, sq = 0.f;
        for (int c = part * 32; c < part * 32 + 32; ++c) {
            float v = Xs[c * 64 + sl];
            sum += v; sq += v * v;
        }
        red[part][sl] = sum; red[4 + part][sl] = sq;
    }
    __syncthreads();
    if (tid < 64) {
        float s = red[0][tid] + red[1][tid] + red[2][tid] + red[3][tid];
        float q = red[4][tid] + red[5][tid] + red[6][tid] + red[7][tid];
        float mu = s * (1.f / 128.f);
        float var = q * (1.f / 128.f) - mu * mu;
        mu_s[tid] = mu;
        rs_s[tid] = rsqrtf(var + 1e-5f);
    }
    __syncthreads();
    // normalize -> Aln bf16, XOR-swizzled 16B chunks within each 256B row
#pragma unroll
    for (int i = 0; i < 16; ++i) {
        int idx = tid + i * 256;           // 4096 = 64 cpair x 64 s
        int sl = idx & 63, cp = idx >> 6;
        int c = cp * 2;
        float mu = mu_s[sl], rs = rs_s[sl];
        float v0 = (Xs[c * 64 + sl] - mu) * rs * gm[c] + bt[c];
        float v1 = (Xs[(c + 1) * 64 + sl] - mu) * rs * gm[c + 1] + bt[c + 1];
        unsigned int pk = (unsigned int)f2bf(v0) | ((unsigned int)f2bf(v1) << 16);
        int chunk = (c >> 3) ^ (sl & 7);
        ((unsigned int*)Aln)[sl * 64 + chunk * 4 + ((c & 7) >> 1)] = pk;
    }
    __syncthreads();                       // Xs dead from here; Wl alias live

    const int lane = tid & 63;
    const int w = tid >> 6;
    const float* W = (which == 0) ? wq : (wkv + (size_t)(which - 1) * DIMC * DIMC);
#pragma unroll
    for (int i = 0; i < 32; ++i) {     // weights [n][c] fp32 -> bf16 swizzled LDS
        int idx = tid + i * 256;
        int cp = idx & 63, n = idx >> 6, c = cp * 2;
        float2 wv = *(const float2*)(W + n * DIMC + c);
        unsigned int pk = (unsigned int)f2bf(wv.x) | ((unsigned int)f2bf(wv.y) << 16);
        int chunk = (c >> 3) ^ (n & 7);
        ((unsigned int*)Wl)[n * 64 + chunk * 4 + ((c & 7) >> 1)] = pk;
    }
    __syncthreads();
    f4 acc[8];
#pragma unroll
    for (int nt = 0; nt < 8; ++nt) { acc[nt][0]=0.f; acc[nt][1]=0.f; acc[nt][2]=0.f; acc[nt][3]=0.f; }
#pragma unroll
    for (int kk = 0; kk < 4; ++kk) {
        int arow = w * 16 + (lane & 15);
        int ach = (kk * 4 + (lane >> 4)) ^ (arow & 7);
        bf8 af = *(const bf8*)(Aln + arow * DIMC + ach * 8);
#pragma unroll
        for (int nt = 0; nt < 8; ++nt) {
            int brow = nt * 16 + (lane & 15);
            int bch = (kk * 4 + (lane >> 4)) ^ (brow & 7);
            bf8 bfr = *(const bf8*)(Wl + brow * DIMC + bch * 8);
            acc[nt] = __builtin_amdgcn_mfma_f32_16x16x32_bf16(af, bfr, acc[nt], 0, 0, 0);
        }
    }
    // epilogue: C layout col=lane&15 (=n within tile=d), row=(lane>>4)*4+r (=s)
    int d = lane & 15;
    int sloc = s0 + w * 16 + ((lane >> 4) << 2);
#pragma unroll
    for (int nt = 0; nt < 8; ++nt) {
        int headg = b * NHEAD + nt;    // head == nt (16-wide n-tiles)
        if (which == 0) {
            const float QSC = 0.25f * 1.44269504088896f;  // fold scale*log2e into Q
#pragma unroll
            for (int r2 = 0; r2 < 4; ++r2)
                qo[((size_t)headg * S_LEN + sloc + r2) * HDIM + d] = f2bf(acc[nt][r2] * QSC);
        } else if (which == 1) {
#pragma unroll
            for (int r2 = 0; r2 < 4; ++r2)
                ko[((size_t)headg * S_LEN + sloc + r2) * HDIM + d] = f2bf(acc[nt][r2]);
        } else {
            u16x4 pv;
#pragma unroll
            for (int r2 = 0; r2 < 4; ++r2) pv[r2] = f2bf(acc[nt][r2]);
            *(u16x4*)(vto + ((size_t)headg * HDIM + d) * S_LEN + sloc) = pv;   // V^T [bh][d][s]
        }
    }
}

// ---------------- Kernel 2: flash attention, fixed m=0 (no max tracking) ----------------
// R13-verified tail: p=exp2(st) directly (LN-bounded scores), f32 lsum, end-normalize.
static __device__ __forceinline__ void attn_tail(
    f16v& st, const bf8& vfA, const bf8& vfB, float& lsum_h, f16v& o)
{
#pragma unroll
    for (int r = 0; r < 16; ++r) st[r] = __builtin_amdgcn_exp2f(st[r]);
    float q0 = (st[0] + st[1]) + (st[2] + st[3]);
    float q1 = (st[4] + st[5]) + (st[6] + st[7]);
    float q2 = (st[8] + st[9]) + (st[10] + st[11]);
    float q3 = (st[12] + st[13]) + (st[14] + st[15]);
    lsum_h += (q0 + q1) + (q2 + q3);   // per-half partial; cross-half combine deferred
    // pack P^T B-frags (R2-verified): kp chunk 0..15
    unsigned a0 = cvtpk(st[0], st[1]);
    unsigned a1 = cvtpk(st[2], st[3]);
    unsigned a2 = cvtpk(st[4], st[5]);
    unsigned a3 = cvtpk(st[6], st[7]);
    plswap(a0, a2); plswap(a1, a3);
    u32x4 tA; tA[0] = a0; tA[1] = a1; tA[2] = a2; tA[3] = a3;
    o = __builtin_amdgcn_mfma_f32_32x32x16_bf16(vfA, __builtin_bit_cast(bf8, tA), o, 0, 0, 0);
    // kp chunk 16..31
    unsigned b0 = cvtpk(st[8], st[9]);
    unsigned b1 = cvtpk(st[10], st[11]);
    unsigned b2 = cvtpk(st[12], st[13]);
    unsigned b3 = cvtpk(st[14], st[15]);
    plswap(b0, b2); plswap(b1, b3);
    u32x4 tB; tB[0] = b0; tB[1] = b1; tB[2] = b2; tB[3] = b3;
    o = __builtin_amdgcn_mfma_f32_32x32x16_bf16(vfB, __builtin_bit_cast(bf8, tB), o, 0, 0, 0);
}

// grid 512*NS linear (XCD-swizzled); block 2 waves * 64 q-rows
template <int NS>
__global__ __launch_bounds__(128, 4) void k_attn(
    const unsigned short* __restrict__ qo,
    const unsigned short* __restrict__ ko,
    const unsigned short* __restrict__ vto,
    unsigned short* __restrict__ xo,
    float* __restrict__ opart, float* __restrict__ lpart)
{
    const int tid = threadIdx.x;
    const int lane = tid & 63;
    const int w = tid >> 6;                  // 0..1
    // XCD-aware remap: all 64*NS blocks of a bh land on one XCD (2 bh per XCD);
    // per-bh K/V (256KB) stays L2-resident (R8-verified: FETCH 17.8 -> 3.1 MB).
    const int lid = blockIdx.x;              // [0, 512*NS)
    const int xcd = lid & 7;
    const int j = lid >> 3;                  // [0, 64*NS)
    const int bh = xcd * 2 + j / (32 * NS);
    const int r = j % (32 * NS);
    const int qb = r & 31;                   // 32 q-tiles of 128
    const int sp = r >> 5;                   // [0, NS)
    const int s0 = qb * 128 + w * 64;
    const int b = bh >> 3, h = bh & 7;
    const int kt0 = sp * (S_LEN / NS);
    const int kt1 = kt0 + S_LEN / NS;

    const unsigned short* Qp = qo + (size_t)bh * S_LEN * HDIM;
    const unsigned short* Kp = ko + (size_t)bh * S_LEN * HDIM;
    const unsigned short* Vp = vto + (size_t)bh * HDIM * S_LEN;

    const int l31 = lane & 31, l15 = lane & 15, hi = lane >> 5;
    const unsigned short* vrow = Vp + (size_t)l15 * S_LEN + hi * 8;

    // Q B-frags for the two q-blocks: lane holds Q[s0(+32)+l31][d = hi*8 + j]
    bf8 qfA = *(const bf8*)(Qp + (size_t)(s0 + l31) * HDIM + hi * 8);
    bf8 qfB = *(const bf8*)(Qp + (size_t)(s0 + 32 + l31) * HDIM + hi * 8);

    float lsumA = 0.f, lsumB = 0.f;
    f16v oA = zero_f16v();              // rows r=0..7 useful (d = (r&3)+8*(r>>2)+4*hi)
    f16v oB = zero_f16v();
    const f16v zacc = zero_f16v();      // single persistent zero C operand

    // prefetch: K one tile ahead, V for tile 0
    bf8 kf   = *(const bf8*)(Kp + (size_t)(kt0 + l31) * HDIM + hi * 8);
    bf8 kf_n = *(const bf8*)(Kp + (size_t)(kt0 + 32 + l31) * HDIM + hi * 8);
    bf8 vfA_c = *(const bf8*)(vrow + kt0);
    bf8 vfB_c = *(const bf8*)(vrow + kt0 + 16);

    for (int kt = kt0; kt < kt1; kt += 32) {
        f16v stA = __builtin_amdgcn_mfma_f32_32x32x16_bf16(kf, qfA, zacc, 0, 0, 0);
        bf8 kf_n2 = *(const bf8*)(Kp + (size_t)(kt + 64 + l31) * HDIM + hi * 8); // tail overread in ws
        bf8 vfA_n = *(const bf8*)(vrow + kt + 32);
        bf8 vfB_n = *(const bf8*)(vrow + kt + 48);
        attn_tail(stA, vfA_c, vfB_c, lsumA, oA);
        f16v stB = __builtin_amdgcn_mfma_f32_32x32x16_bf16(kf, qfB, zacc, 0, 0, 0);
        attn_tail(stB, vfA_c, vfB_c, lsumB, oB);

        kf = kf_n; kf_n = kf_n2;
        vfA_c = vfA_n; vfB_c = vfB_n;
    }

    float lsA = lsumA + __shfl_xor(lsumA, 32);   // deferred cross-half combine
    float lsB = lsumB + __shfl_xor(lsumB, 32);

    if (NS == 1) {
        float invA = 1.f / lsA, invB = 1.f / lsB;
        u16x4 a_lo, a_hi, b_lo, b_hi;
#pragma unroll
        for (int r2 = 0; r2 < 4; ++r2) {
            a_lo[r2] = f2bf(oA[r2] * invA);
            a_hi[r2] = f2bf(oA[r2 + 4] * invA);
            b_lo[r2] = f2bf(oB[r2] * invB);
            b_hi[r2] = f2bf(oB[r2 + 4] * invB);
        }
        size_t baseA = ((size_t)b * S_LEN + s0 + l31) * DIMC + h * HDIM;
        size_t baseB = ((size_t)b * S_LEN + s0 + 32 + l31) * DIMC + h * HDIM;
        *(u16x4*)(xo + baseA + 4 * hi) = a_lo;
        *(u16x4*)(xo + baseA + 8 + 4 * hi) = a_hi;
        *(u16x4*)(xo + baseB + 4 * hi) = b_lo;
        *(u16x4*)(xo + baseB + 8 + 4 * hi) = b_hi;
    } else {
        size_t rbA = ((size_t)(sp * 16 + bh) * S_LEN + s0 + l31) * 16;
        size_t rbB = rbA + 32 * 16;
        f4 xa0, xa1, xb0, xb1;
#pragma unroll
        for (int r2 = 0; r2 < 4; ++r2) {
            xa0[r2] = oA[r2]; xa1[r2] = oA[r2 + 4];
            xb0[r2] = oB[r2]; xb1[r2] = oB[r2 + 4];
        }
        *(f4*)(opart + rbA + 4 * hi) = xa0;
        *(f4*)(opart + rbA + 8 + 4 * hi) = xa1;
        *(f4*)(opart + rbB + 4 * hi) = xb0;
        *(f4*)(opart + rbB + 8 + 4 * hi) = xb1;
        if (!hi) {
            lpart[(size_t)(sp * 16 + bh) * S_LEN + s0 + l31] = lsA;
            lpart[(size_t)(sp * 16 + bh) * S_LEN + s0 + 32 + l31] = lsB;
        }
    }
}

// ---------------- Kernel 2b: combine NS KV-splits (NS=1 fallback path only) ----------------
template <int NS>
__global__ __launch_bounds__(256) void k_combine(
    const float* __restrict__ op, const float* __restrict__ lp,
    unsigned short* __restrict__ xo)
{
    int idx = blockIdx.x * 256 + threadIdx.x;   // 262144 = 65536 rows x 4 d-chunks
    int row = idx >> 2;                          // bh*4096 + s
    int dc = (idx & 3) * 4;
    int bh = row >> 12, s = row & 4095;
    int b = bh >> 3, h = bh & 7;
    float den = 0.f;
#pragma unroll
    for (int i = 0; i < NS; ++i) den += lp[row + (size_t)i * (16 << 12)];
    float inv = 1.f / den;
    f4 acc;
#pragma unroll
    for (int jj = 0; jj < 4; ++jj) acc[jj] = 0.f;
#pragma unroll
    for (int i = 0; i < NS; ++i) {
        f4 oi = *(const f4*)(op + ((size_t)row + (size_t)i * (16 << 12)) * 16 + dc);
#pragma unroll
        for (int jj = 0; jj < 4; ++jj) acc[jj] += oi[jj];
    }
    u16x4 rr;
#pragma unroll
    for (int jj = 0; jj < 4; ++jj) rr[jj] = f2bf(acc[jj] * inv);
    *(u16x4*)(xo + ((size_t)b * S_LEN + s) * DIMC + h * HDIM + dc) = rr;
}

// ---------------- Kernel 3 (fused): combine NS splits + projection + bias + [b,c,s] store ----
// A-operand built directly from opart/lp: af covers 8 channels of ONE head
// (c = kk*32 + g4*8 + 0..7 -> h = c>>4, d0 = c&15 in {0,8}).
template <int NS>
__global__ __launch_bounds__(256) void k_proj_fused(
    const float* __restrict__ op, const float* __restrict__ lp,
    const float* __restrict__ wp, const float* __restrict__ bp,
    float* __restrict__ out)
{
    __shared__ __align__(16) unsigned short Wl[64 * DIMC];   // 16KB
    const int tid = threadIdx.x, lane = tid & 63, w = tid >> 6;
    const int m0 = (blockIdx.x >> 1) * 64;
    const int nh = blockIdx.x & 1;
#pragma unroll
    for (int i = 0; i < 16; ++i) {
        int idx = tid + i * 256;
        int cp = idx & 63, n = idx >> 6, c = cp * 2;
        float2 wv = *(const float2*)(wp + (size_t)(nh * 64 + n) * DIMC + c);
        unsigned int pk = (unsigned int)f2bf(wv.x) | ((unsigned int)f2bf(wv.y) << 16);
        int chunk = (c >> 3) ^ (n & 7);
        ((unsigned int*)Wl)[n * 64 + chunk * 4 + ((c & 7) >> 1)] = pk;
    }
    __syncthreads();
    f4 acc[4];
#pragma unroll
    for (int nt = 0; nt < 4; ++nt) { acc[nt][0]=0.f; acc[nt][1]=0.f; acc[nt][2]=0.f; acc[nt][3]=0.f; }
    const int arow = m0 + w * 16 + (lane & 15);
    const int g4 = lane >> 4;
    const int bb0 = arow >> 12, ss0 = arow & 4095;   // batch, seq of this A-row
#pragma unroll
    for (int kk = 0; kk < 4; ++kk) {
        // reconstruct af = x[arow][c0..c0+7] from NS split partials (fixed m=0: plain sums)
        int c0 = kk * 32 + g4 * 8;
        int hh = c0 >> 4;                    // head of these 8 channels
        int d0 = c0 & 15;                    // 0 or 8
        int bh_ = bb0 * NHEAD + hh;
        float den = 0.f;
        f4 alo, ahi;
#pragma unroll
        for (int jj = 0; jj < 4; ++jj) { alo[jj] = 0.f; ahi[jj] = 0.f; }
#pragma unroll
        for (int i = 0; i < NS; ++i) {
            size_t row = (size_t)(i * 16 + bh_) * S_LEN + ss0;
            den += lp[row];
            f4 lo = *(const f4*)(op + row * 16 + d0);
            f4 hi = *(const f4*)(op + row * 16 + d0 + 4);
#pragma unroll
            for (int jj = 0; jj < 4; ++jj) { alo[jj] += lo[jj]; ahi[jj] += hi[jj]; }
        }
        float inv = 1.f / den;
        us8 av;
#pragma unroll
        for (int jj = 0; jj < 4; ++jj) {
            av[jj] = f2bf(alo[jj] * inv);
            av[jj + 4] = f2bf(ahi[jj] * inv);
        }
        bf8 af = __builtin_bit_cast(bf8, av);
#pragma unroll
        for (int nt = 0; nt < 4; ++nt) {
            int brow = nt * 16 + (lane & 15);
            int bch = (kk * 4 + g4) ^ (brow & 7);
            bf8 bfr = *(const bf8*)(Wl + brow * DIMC + bch * 8);
            acc[nt] = __builtin_amdgcn_mfma_f32_16x16x32_bf16(af, bfr, acc[nt], 0, 0, 0);
        }
    }
    int sl0 = m0 + w * 16 + ((lane >> 4) << 2);
    int bb = sl0 >> 12, ss = sl0 & 4095;
#pragma unroll
    for (int nt = 0; nt < 4; ++nt) {
        int n = nh * 64 + nt * 16 + (lane & 15);
        float bias = bp[n];
        f4 v;
#pragma unroll
        for (int r2 = 0; r2 < 4; ++r2) v[r2] = acc[nt][r2] + bias;
        *(f4*)(out + ((size_t)bb * DIMC + n) * S_LEN + ss) = v;   // 4 consecutive s, float4
    }
}

// ---------------- Kernel 3 (NS=1 fallback): projection from xas ----------------
__global__ __launch_bounds__(256) void k_proj(
    const unsigned short* __restrict__ xa, const float* __restrict__ wp,
    const float* __restrict__ bp, float* __restrict__ out)
{
    __shared__ __align__(16) unsigned short Wl[64 * DIMC];   // 16KB
    const int tid = threadIdx.x, lane = tid & 63, w = tid >> 6;
    const int m0 = (blockIdx.x >> 1) * 64;
    const int nh = blockIdx.x & 1;
#pragma unroll
    for (int i = 0; i < 16; ++i) {
        int idx = tid + i * 256;
        int cp = idx & 63, n = idx >> 6, c = cp * 2;
        float2 wv = *(const float2*)(wp + (size_t)(nh * 64 + n) * DIMC + c);
        unsigned int pk = (unsigned int)f2bf(wv.x) | ((unsigned int)f2bf(wv.y) << 16);
        int chunk = (c >> 3) ^ (n & 7);
        ((unsigned int*)Wl)[n * 64 + chunk * 4 + ((c & 7) >> 1)] = pk;
    }
    __syncthreads();
    f4 acc[4];
#pragma unroll
    for (int nt = 0; nt < 4; ++nt) { acc[nt][0]=0.f; acc[nt][1]=0.f; acc[nt][2]=0.f; acc[nt][3]=0.f; }
    int arow = m0 + w * 16 + (lane & 15);
#pragma unroll
    for (int kk = 0; kk < 4; ++kk) {
        bf8 af = *(const bf8*)(xa + (size_t)arow * DIMC + kk * 32 + (lane >> 4) * 8);
#pragma unroll
        for (int nt = 0; nt < 4; ++nt) {
            int brow = nt * 16 + (lane & 15);
            int bch = (kk * 4 + (lane >> 4)) ^ (brow & 7);
            bf8 bfr = *(const bf8*)(Wl + brow * DIMC + bch * 8);
            acc[nt] = __builtin_amdgcn_mfma_f32_16x16x32_bf16(af, bfr, acc[nt], 0, 0, 0);
        }
    }
    int sl0 = m0 + w * 16 + ((lane >> 4) << 2);
    int bb = sl0 >> 12, ss = sl0 & 4095;
#pragma unroll
    for (int nt = 0; nt < 4; ++nt) {
        int n = nh * 64 + nt * 16 + (lane & 15);
        float bias = bp[n];
        f4 v;
#pragma unroll
        for (int r2 = 0; r2 < 4; ++r2) v[r2] = acc[nt][r2] + bias;
        *(f4*)(out + ((size_t)bb * DIMC + n) * S_LEN + ss) = v;   // 4 consecutive s, float4
    }
}

extern "C" void kernel_launch(void* const* d_in, const int* in_sizes, int n_in,
                              void* d_out, int out_size, void* d_ws, size_t ws_size,
                              hipStream_t stream) {
    const float* feat_a = (const float*)d_in[0];
    const float* feat_b = (const float*)d_in[1];
    const float* wq     = (const float*)d_in[2];
    const float* wkv    = (const float*)d_in[3];
    const float* wproj  = (const float*)d_in[4];
    const float* bproj  = (const float*)d_in[5];
    const float* g1     = (const float*)d_in[6];
    const float* b1     = (const float*)d_in[7];
    const float* g2     = (const float*)d_in[8];
    const float* b2     = (const float*)d_in[9];
    const float* pos    = (const float*)d_in[10];
    float* out = (float*)d_out;

    unsigned short* ws = (unsigned short*)d_ws;
    unsigned short* qs  = ws;                    // 2MB bf16 [16][4096][16]
    unsigned short* kss = ws + (1u << 20);       // 2MB
    unsigned short* vts = ws + (2u << 20);       // 2MB V^T [16][16][4096]
    unsigned short* xas = ws + (3u << 20);       // 2MB attn out bf16 (NS=1 path)
    float*  opart = (float*)(ws + (4u << 20));   // NS*4MB f32 at byte 8MB
    float*  lp2   = (float*)(ws + (8u << 20));   // bytes 16..16.5MB (NS=2)
    float*  lp4   = (float*)(ws + (12u << 20));  // bytes 24..25MB (NS=4)

    k_lnqkv<<<dim3(384), dim3(256), 0, stream>>>(feat_a, feat_b, wq, wkv, g1, b1, g2, b2, pos,
                                                 qs, kss, vts);
    if (ws_size >= ((size_t)26 << 20)) {         // NS=4 (R18-verified best: 68.34 us)
        k_attn<4><<<dim3(2048), dim3(128), 0, stream>>>(qs, kss, vts, xas, opart, lp4);
        k_proj_fused<4><<<dim3(256), dim3(256), 0, stream>>>(opart, lp4, wproj, bproj, out);
    } else if (ws_size >= ((size_t)18 << 20)) {
        k_attn<2><<<dim3(1024), dim3(128), 0, stream>>>(qs, kss, vts, xas, opart, lp2);
        k_proj_fused<2><<<dim3(256), dim3(256), 0, stream>>>(opart, lp2, wproj, bproj, out);
    } else {
        k_attn<1><<<dim3(512), dim3(128), 0, stream>>>(qs, kss, vts, xas, opart, lp2);
        k_proj<<<dim3(256), dim3(256), 0, stream>>>(xas, wproj, bproj, out);
    }
}